// Round 14
// baseline (1858.817 us; speedup 1.0000x reference)
//
#include <hip/hip_runtime.h>
#include <hip/hip_bf16.h>

constexpr int N = 16384;   // points
constexpr int KNN = 10;
constexpr int CF = 64;     // feature channels per edgeconv
constexpr int NS64 = 16;   // col splits for knn64 (grid 64*16 = 1024 = 4 blocks/CU)
constexpr int NS3 = 12;    // col splits for knn3  (grid 64*12 = 768)

#define FBIG 1e30f

typedef __attribute__((ext_vector_type(8))) __bf16 bfv8;
typedef __attribute__((ext_vector_type(4))) float f32x4;

// ---------- top-k insert (replace-max) ----------
#define TOPK_INSERT(dval, jval)                                            \
  if ((dval) < bmax) {                                                     \
    float mv = bd[0]; int slot = 0;                                        \
    _Pragma("unroll") for (int s_ = 1; s_ < 10; ++s_)                      \
      if (bd[s_] > mv) { mv = bd[s_]; slot = s_; }                         \
    _Pragma("unroll") for (int s_ = 0; s_ < 10; ++s_)                      \
      if (slot == s_) { bd[s_] = (dval); bi[s_] = (jval); }                \
    bmax = bd[0];                                                          \
    _Pragma("unroll") for (int s_ = 1; s_ < 10; ++s_)                      \
      bmax = fmaxf(bmax, bd[s_]);                                          \
  }

__device__ inline ushort bf16_rne(float x) {
  unsigned u = __float_as_uint(x);
  return (ushort)((u + 0x7FFFu + ((u >> 16) & 1u)) >> 16);
}
__device__ inline float bf16_to_f(ushort h) { return __uint_as_float(((unsigned)h) << 16); }

// ---------- pack x (3ch) into float4 with sq norm; init gtau + accum ----------
__global__ __launch_bounds__(256) void pack3_kernel(const float* __restrict__ X,
                                                    float4* __restrict__ xp,
                                                    int* __restrict__ gtauI,
                                                    float* __restrict__ accum) {
  int i = blockIdx.x * 256 + threadIdx.x;
  float x0 = X[3 * i], x1 = X[3 * i + 1], x2 = X[3 * i + 2];
  float s = fmaf(x0, x0, fmaf(x1, x1, x2 * x2));
  xp[i] = make_float4(x0, x1, x2, s);
  gtauI[i] = 0x7F7F7F7F;  // ~3.39e38
  if (blockIdx.x == 0 && threadIdx.x < 128) accum[threadIdx.x] = 0.f;
}

// ---------- fused 64-ch prep: bf16 hi/lo split + sq norm; init gtau + accum ----------
__global__ __launch_bounds__(256) void prep128s_kernel(const float* __restrict__ X,
                                                       ushort* __restrict__ Xp,
                                                       float* __restrict__ sq,
                                                       int* __restrict__ gtauI,
                                                       float* __restrict__ accum) {
  int i = blockIdx.x * 256 + threadIdx.x;
  int n = i >> 4, k4 = (i & 15) << 2;
  float4 v = ((const float4*)X)[i];
  float vv[4] = {v.x, v.y, v.z, v.w};
  ushort h[4], lo[4];
#pragma unroll
  for (int k = 0; k < 4; ++k) {
    h[k] = bf16_rne(vv[k]);
    lo[k] = bf16_rne(vv[k] - bf16_to_f(h[k]));
  }
  ushort* row = Xp + (size_t)n * 128;
  *(ushort4*)(row + k4) = make_ushort4(h[0], h[1], h[2], h[3]);
  *(ushort4*)(row + 64 + k4) = make_ushort4(lo[0], lo[1], lo[2], lo[3]);
  float ps = fmaf(vv[0], vv[0], fmaf(vv[1], vv[1], fmaf(vv[2], vv[2], vv[3] * vv[3])));
#pragma unroll
  for (int m = 1; m < 16; m <<= 1) ps += __shfl_xor(ps, m, 16);
  if ((threadIdx.x & 15) == 0) {
    sq[n] = ps;
    gtauI[n] = 0x7F7F7F7F;
  }
  if (blockIdx.x == 0 && threadIdx.x < 128) accum[threadIdx.x] = 0.f;
}

// ---------- kNN for C=64 via bf16-split MFMA: 16-col chunks, 4 blocks/CU ----------
// r11-measured body; occupancy raised 3->4 blocks/CU (LDS 28.7KB*4=114.7KB, VGPR 84).
__global__ __launch_bounds__(256, 4) void knn64w_kernel(const ushort* __restrict__ Xp,
                                                        const float* __restrict__ sq,
                                                        int* __restrict__ gtauI,
                                                        float* __restrict__ dpart,
                                                        ushort* __restrict__ ipart) {
  __shared__ float bufD[4][64 * 17];
  __shared__ ushort bufI[4][64 * 18];
  __shared__ __align__(16) float tauS[4][64];
  __shared__ int cntS[4][64];

  const int tid = threadIdx.x;
  const int w = tid >> 6, l = tid & 63, lp = l & 15, g = l >> 4;
  const int rg = blockIdx.x / NS64, cs = blockIdx.x % NS64;
  const int wbase = rg * 256 + w * 64;
  const int myrow = wbase + l;
  const int c0 = (1024 * cs) / NS64, c1 = (1024 * (cs + 1)) / NS64;  // 16-col chunks

  tauS[w][l] = FBIG;
  cntS[w][l] = 0;
  __builtin_amdgcn_wave_barrier();

  // A fragments: 4 row-tiles (rows wbase + rt*16 + lp, k-slice g*8)
  bfv8 aH1[4], aH2[4], aL1[4], aL2[4];
#pragma unroll
  for (int rt = 0; rt < 4; ++rt) {
    const size_t ao = (size_t)(wbase + rt * 16 + lp) * 128 + g * 8;
    aH1[rt] = *(const bfv8*)&Xp[ao];
    aH2[rt] = *(const bfv8*)&Xp[ao + 32];
    aL1[rt] = *(const bfv8*)&Xp[ao + 64];
    aL2[rt] = *(const bfv8*)&Xp[ao + 96];
  }
  float sqi[16];
#pragma unroll
  for (int rt = 0; rt < 4; ++rt)
#pragma unroll
    for (int r = 0; r < 4; ++r) sqi[rt * 4 + r] = sq[wbase + rt * 16 + g * 4 + r];

  float bd[10]; int bi[10]; float bmax = FBIG; float lastPub = FBIG;
#pragma unroll
  for (int s = 0; s < 10; ++s) { bd[s] = FBIG; bi[s] = 0x7fffffff; }
  int gt = 0x7F7F7F7F;

  for (int t = c0; t < c1; ++t) {
    const int bcol = t * 16 + lp;
    const size_t bo = (size_t)bcol * 128 + g * 8;
    bfv8 bc0 = *(const bfv8*)&Xp[bo];
    bfv8 bc1 = *(const bfv8*)&Xp[bo + 32];
    bfv8 bc2 = *(const bfv8*)&Xp[bo + 64];
    bfv8 bc3 = *(const bfv8*)&Xp[bo + 96];
    float sjc = sq[bcol];
    int gtn = gtauI[myrow];

    __builtin_amdgcn_wave_barrier();
    {  // drain prev chunk: every lane owns row l
      const int c = cntS[w][l];
      if (c) {
        const float* bD = &bufD[w][l * 17];
        const ushort* bI = &bufI[w][l * 18];
#pragma unroll 1
        for (int j = 0; j < c; ++j) {
          float d = bD[j];
          int ii = (int)bI[j];
          TOPK_INSERT(d, ii);
        }
        cntS[w][l] = 0;
      }
      tauS[w][l] = fminf(bmax, __int_as_float(gt));
      if (bmax < lastPub) {  // publish only on improvement
        atomicMin(&gtauI[myrow], __float_as_int(bmax));
        lastPub = bmax;
      }
    }
    __builtin_amdgcn_wave_barrier();
    gt = gtn;

#pragma unroll
    for (int rt = 0; rt < 4; ++rt) {
      f32x4 acc = {0.f, 0.f, 0.f, 0.f};
      acc = __builtin_amdgcn_mfma_f32_16x16x32_bf16(aH1[rt], bc0, acc, 0, 0, 0);
      acc = __builtin_amdgcn_mfma_f32_16x16x32_bf16(aH2[rt], bc1, acc, 0, 0, 0);
      acc = __builtin_amdgcn_mfma_f32_16x16x32_bf16(aH1[rt], bc2, acc, 0, 0, 0);
      acc = __builtin_amdgcn_mfma_f32_16x16x32_bf16(aH2[rt], bc3, acc, 0, 0, 0);
      acc = __builtin_amdgcn_mfma_f32_16x16x32_bf16(aL1[rt], bc0, acc, 0, 0, 0);
      acc = __builtin_amdgcn_mfma_f32_16x16x32_bf16(aL2[rt], bc1, acc, 0, 0, 0);
      f32x4 taur = *(const f32x4*)&tauS[w][rt * 16 + g * 4];
#pragma unroll
      for (int r = 0; r < 4; ++r) {
        float d = fmaf(-2.f, acc[r], sqi[rt * 4 + r] + sjc);
        if (d < taur[r]) {
          int rloc = rt * 16 + g * 4 + r;
          int pos = atomicAdd(&cntS[w][rloc], 1);
          bufD[w][rloc * 17 + pos] = d;
          bufI[w][rloc * 18 + pos] = (ushort)bcol;
        }
      }
    }
  }

  __builtin_amdgcn_wave_barrier();
  {  // final drain
    const int c = cntS[w][l];
    const float* bD = &bufD[w][l * 17];
    const ushort* bI = &bufI[w][l * 18];
#pragma unroll 1
    for (int j = 0; j < c; ++j) {
      float d = bD[j];
      int ii = (int)bI[j];
      TOPK_INSERT(d, ii);
    }
  }
  float* dp = dpart + ((size_t)cs * N + myrow) * 10;
  ushort* ip = ipart + ((size_t)cs * N + myrow) * 10;
#pragma unroll
  for (int s = 0; s < 10; ++s) { dp[s] = bd[s]; ip[s] = (ushort)bi[s]; }
}

// ---------- kNN for C=3, exact fp32 (cancellation-sensitive: keep fp32!) ----------
// r11-measured version: 64 rows/wave, 16-col chunks, global tau.
__global__ __launch_bounds__(256, 3) void knn3g_kernel(const float4* __restrict__ xp,
                                                       int* __restrict__ gtauI,
                                                       float* __restrict__ dpart,
                                                       ushort* __restrict__ ipart) {
  __shared__ float bufD[4][64 * 17];
  __shared__ ushort bufI[4][64 * 18];
  __shared__ __align__(16) float tauS[4][64];
  __shared__ int cntS[4][64];

  const int tid = threadIdx.x;
  const int w = tid >> 6, l = tid & 63, lp = l & 15, g = l >> 4;
  const int rg = blockIdx.x / NS3, cs = blockIdx.x % NS3;
  const int wbase = rg * 256 + w * 64;
  const int myrow = wbase + l;
  const int c0 = (1024 * cs) / NS3, c1 = (1024 * (cs + 1)) / NS3;

  tauS[w][l] = FBIG;
  cntS[w][l] = 0;
  __builtin_amdgcn_wave_barrier();

  // 16 pinned row float4s: rows wbase + rt*16 + g*4 + r
  float4 rw[16];
#pragma unroll
  for (int rt = 0; rt < 4; ++rt)
#pragma unroll
    for (int r = 0; r < 4; ++r) rw[rt * 4 + r] = xp[wbase + rt * 16 + g * 4 + r];

  float bd[10]; int bi[10]; float bmax = FBIG; float lastPub = FBIG;
#pragma unroll
  for (int s = 0; s < 10; ++s) { bd[s] = FBIG; bi[s] = 0x7fffffff; }
  int gt = 0x7F7F7F7F;

  for (int t = c0; t < c1; ++t) {
    const int bcol = t * 16 + lp;
    const float4 oc = xp[bcol];
    int gtn = gtauI[myrow];

    __builtin_amdgcn_wave_barrier();
    {  // drain prev chunk
      const int c = cntS[w][l];
      if (c) {
        const float* bD = &bufD[w][l * 17];
        const ushort* bI = &bufI[w][l * 18];
#pragma unroll 1
        for (int j = 0; j < c; ++j) {
          float d = bD[j];
          int ii = (int)bI[j];
          TOPK_INSERT(d, ii);
        }
        cntS[w][l] = 0;
      }
      tauS[w][l] = fminf(bmax, __int_as_float(gt));
      if (bmax < lastPub) {
        atomicMin(&gtauI[myrow], __float_as_int(bmax));
        lastPub = bmax;
      }
    }
    __builtin_amdgcn_wave_barrier();
    gt = gtn;

#pragma unroll
    for (int rt = 0; rt < 4; ++rt) {
      f32x4 taur = *(const f32x4*)&tauS[w][rt * 16 + g * 4];
#pragma unroll
      for (int r = 0; r < 4; ++r) {
        const float4 m = rw[rt * 4 + r];
        float dot = fmaf(m.x, oc.x, fmaf(m.y, oc.y, m.z * oc.z));
        float d = fmaf(-2.f, dot, m.w + oc.w);  // same chain as validated knn3
        if (d < taur[r]) {
          int rloc = rt * 16 + g * 4 + r;
          int pos = atomicAdd(&cntS[w][rloc], 1);
          bufD[w][rloc * 17 + pos] = d;
          bufI[w][rloc * 18 + pos] = (ushort)bcol;
        }
      }
    }
  }

  __builtin_amdgcn_wave_barrier();
  {  // final drain
    const int c = cntS[w][l];
    const float* bD = &bufD[w][l * 17];
    const ushort* bI = &bufI[w][l * 18];
#pragma unroll 1
    for (int j = 0; j < c; ++j) {
      float d = bD[j];
      int ii = (int)bI[j];
      TOPK_INSERT(d, ii);
    }
  }
  float* dp = dpart + ((size_t)cs * N + myrow) * 10;
  ushort* ip = ipart + ((size_t)cs * N + myrow) * 10;
#pragma unroll
  for (int s = 0; s < 10; ++s) { dp[s] = bd[s]; ip[s] = (ushort)bi[s]; }
}

// ---------- merge S partial top-10 lists per row (r11-measured version) ----------
template <int S>
__global__ __launch_bounds__(256) void merge_kernel(const float* __restrict__ dpart,
                                                    const ushort* __restrict__ ipart,
                                                    ushort* __restrict__ idx_out) {
  const int row = blockIdx.x * 256 + threadIdx.x;
  float d[S * 10]; int id_[S * 10];
#pragma unroll
  for (int p = 0; p < S; ++p)
#pragma unroll
    for (int s = 0; s < 10; ++s) {
      d[p * 10 + s] = dpart[((size_t)p * N + row) * 10 + s];
      id_[p * 10 + s] = (int)ipart[((size_t)p * N + row) * 10 + s];
    }
#pragma unroll
  for (int t = 0; t < 10; ++t) {
    float dm = d[0]; int im = id_[0]; int slot = 0;
#pragma unroll
    for (int e = 1; e < S * 10; ++e) {
      bool better = (d[e] < dm) || (d[e] == dm && id_[e] < im);
      if (better) { dm = d[e]; im = id_[e]; slot = e; }
    }
    idx_out[(size_t)row * 10 + t] = (ushort)im;
#pragma unroll
    for (int e = 0; e < S * 10; ++e)
      if (e == slot) d[e] = FBIG;
  }
}

// ---------- u = x*W_bot ; v = x*(W_top - W_bot) + b ----------
__global__ __launch_bounds__(256) void uv_kernel(const float* __restrict__ Xf, int CIN,
                                                 const float* __restrict__ W,
                                                 const float* __restrict__ bias,
                                                 float* __restrict__ U, float* __restrict__ V) {
  int tid = threadIdx.x;
  int c = tid & 63, p = tid >> 6;
  int n = blockIdx.x * 4 + p;
  const float* xr = Xf + (size_t)n * CIN;
  float vt = 0.f, vb = 0.f;
  for (int m = 0; m < CIN; ++m) {
    float xm = xr[m];
    vt = fmaf(xm, W[m * 64 + c], vt);
    vb = fmaf(xm, W[(CIN + m) * 64 + c], vb);
  }
  U[(size_t)n * 64 + c] = vb;
  V[(size_t)n * 64 + c] = vt - vb + bias[c];
}

// ---------- BN batch stats ----------
__global__ __launch_bounds__(256) void stats_kernel(const float* __restrict__ U,
                                                    const float* __restrict__ V,
                                                    const ushort* __restrict__ idx,
                                                    float* __restrict__ accum) {
  int tid = threadIdx.x;
  int c = tid & 63, p = tid >> 6;
  int base = blockIdx.x * 64;  // 256 blocks x 64 points
  float s = 0.f, s2 = 0.f;
  for (int ch = 0; ch < 16; ++ch) {
    int n = base + ch * 4 + p;
    float vn = V[(size_t)n * 64 + c];
    const ushort* in_ = idx + (size_t)n * 10;
#pragma unroll
    for (int k = 0; k < 10; ++k) {
      float h = vn + U[(size_t)in_[k] * 64 + c];
      s += h;
      s2 = fmaf(h, h, s2);
    }
  }
  __shared__ float red[256], red2[256];
  red[tid] = s; red2[tid] = s2;
  __syncthreads();
  if (tid < 64) {
    float ts = red[tid] + red[64 + tid] + red[128 + tid] + red[192 + tid];
    float t2 = red2[tid] + red2[64 + tid] + red2[128 + tid] + red2[192 + tid];
    atomicAdd(&accum[tid], ts);
    atomicAdd(&accum[64 + tid], t2);
  }
}

__global__ void bnfin_kernel(const float* __restrict__ accum,
                             const float* __restrict__ gamma,
                             const float* __restrict__ beta,
                             float* __restrict__ scale, float* __restrict__ shift) {
  int c = threadIdx.x;  // 64
  float inv = 1.f / (float)(N * KNN);
  float mu = accum[c] * inv;
  float var = accum[64 + c] * inv - mu * mu;
  float sc = gamma[c] * rsqrtf(var + 1e-5f);
  scale[c] = sc;
  shift[c] = fmaf(-mu, sc, beta[c]);
}

// ---------- apply (BN) + ReLU + max over k ----------
__global__ __launch_bounds__(256) void apply_kernel(const float* __restrict__ U,
                                                    const float* __restrict__ V,
                                                    const ushort* __restrict__ idx,
                                                    const float* __restrict__ scale,
                                                    const float* __restrict__ shift,
                                                    int use_bn, float* __restrict__ Fout) {
  int tid = threadIdx.x;
  int c = tid & 63, p = tid >> 6;
  int n = blockIdx.x * 4 + p;
  float sc = use_bn ? scale[c] : 1.f;
  float sh = use_bn ? shift[c] : 0.f;
  float vn = V[(size_t)n * 64 + c];
  const ushort* in_ = idx + (size_t)n * 10;
  float m = 0.f;
#pragma unroll
  for (int k = 0; k < 10; ++k) {
    float h = vn + U[(size_t)in_[k] * 64 + c];
    m = fmaxf(m, fmaf(h, sc, sh));
  }
  Fout[(size_t)n * 64 + c] = m;
}

// ---------- segment max pooling, stage 1 (stage 2 fused into head) ----------
__global__ __launch_bounds__(256) void pool1_kernel(const float* __restrict__ f1,
                                                    const float* __restrict__ f2,
                                                    const float* __restrict__ f3,
                                                    const float* __restrict__ f4,
                                                    const int* __restrict__ n_pts,
                                                    float* __restrict__ Pp) {
  int b = blockIdx.x >> 2;
  int q = blockIdx.x & 3;
  int c = threadIdx.x;
  int off = 0;
  for (int i = 0; i < b; ++i) off += n_pts[i];
  int cnt_ = n_pts[b];
  int s0 = off + (cnt_ * q) / 4;
  int s1 = off + (cnt_ * (q + 1)) / 4;
  const float* f = (c < 64) ? f1 : (c < 128) ? f2 : (c < 192) ? f3 : f4;
  int ch = c & 63;
  float m = -3.4e38f;
  for (int t = s0; t < s1; ++t) m = fmaxf(m, f[(size_t)t * 64 + ch]);
  Pp[((size_t)q * 64 + b) * 256 + c] = m;
}

// ---------- head: 4-way pool max + tanh(P@Wp + bp) + L2 normalize ----------
__global__ __launch_bounds__(128) void head_kernel(const float* __restrict__ Pp,
                                                   const float* __restrict__ Wp,
                                                   const float* __restrict__ bp,
                                                   float* __restrict__ out) {
  int b = blockIdx.x;
  int c = threadIdx.x;
  __shared__ float ps[256];
#pragma unroll
  for (int j = 0; j < 2; ++j) {
    int cc = c + j * 128;
    float m = Pp[(size_t)b * 256 + cc];
#pragma unroll
    for (int q = 1; q < 4; ++q) m = fmaxf(m, Pp[((size_t)q * 64 + b) * 256 + cc]);
    ps[cc] = m;
  }
  __syncthreads();
  float acc = bp[c];
  for (int m = 0; m < 256; ++m) acc = fmaf(ps[m], Wp[m * 128 + c], acc);
  float t = tanhf(acc);
  __shared__ float red[128];
  red[c] = t * t;
  __syncthreads();
  for (int s = 64; s > 0; s >>= 1) {
    if (c < s) red[c] += red[c + s];
    __syncthreads();
  }
  float nrm = sqrtf(red[0]);
  out[b * 128 + c] = t / (nrm + 1e-9f);
}

extern "C" void kernel_launch(void* const* d_in, const int* in_sizes, int n_in,
                              void* d_out, int out_size, void* d_ws, size_t ws_size,
                              hipStream_t stream) {
  const float* x = (const float*)d_in[0];
  const int* n_pts = (const int*)d_in[1];
  const float* W1 = (const float*)d_in[2];
  const float* b1 = (const float*)d_in[3];
  const float* g1 = (const float*)d_in[4];
  const float* be1 = (const float*)d_in[5];
  const float* W2 = (const float*)d_in[6];
  const float* b2 = (const float*)d_in[7];
  const float* W3 = (const float*)d_in[8];
  const float* b3 = (const float*)d_in[9];
  const float* g3 = (const float*)d_in[10];
  const float* be3 = (const float*)d_in[11];
  const float* W4 = (const float*)d_in[12];
  const float* b4 = (const float*)d_in[13];
  const float* Wp = (const float*)d_in[14];
  const float* bp = (const float*)d_in[15];
  float* out = (float*)d_out;

  char* w = (char*)d_ws;
  auto alloc = [&](size_t bytes) {
    char* p = w;
    w += (bytes + 255) & ~(size_t)255;
    return p;
  };
  const size_t FS = (size_t)N * 64 * 4;
  float* f1 = (float*)alloc(FS);
  float* f2 = (float*)alloc(FS);
  float* f3 = (float*)alloc(FS);
  float* f4 = (float*)alloc(FS);
  float* Ub = (float*)alloc(FS);                              // overlaid: Xp128
  float* dpartf = (float*)alloc((size_t)NS64 * N * 10 * 4);   // 10.5 MB
  ushort* iparti = (ushort*)alloc((size_t)NS64 * N * 10 * 2); // 5.2 MB
  float4* xp = (float4*)alloc((size_t)N * 16);
  float* sqb = (float*)alloc((size_t)N * 4);
  int* gtauI = (int*)alloc((size_t)N * 4);
  ushort* idxb = (ushort*)alloc((size_t)N * 10 * 2);
  float* accum = (float*)alloc(512);
  float* scaleb = (float*)alloc(256);
  float* shiftb = (float*)alloc(256);
  float* Ppart = (float*)alloc((size_t)4 * 64 * 256 * 4);
  ushort* Xp128 = (ushort*)Ub;
  // V overlays dpart's first 4 MB: dpart consumed by merge BEFORE uv writes V;
  // V consumed by stats/apply BEFORE the next layer's knn writes dpart.
  float* Vb = dpartf;
  (void)ws_size; (void)n_in; (void)in_sizes; (void)out_size;

  auto run_layer = [&](const float* fin, int cin, const float* W, const float* b,
                       const float* g, const float* be, int use_bn, float* fout) {
    if (cin == 3) {
      pack3_kernel<<<N / 256, 256, 0, stream>>>(fin, xp, gtauI, accum);
      knn3g_kernel<<<64 * NS3, 256, 0, stream>>>(xp, gtauI, dpartf, iparti);
      merge_kernel<NS3><<<N / 256, 256, 0, stream>>>(dpartf, iparti, idxb);
    } else {
      prep128s_kernel<<<N * 64 / 4 / 256, 256, 0, stream>>>(fin, Xp128, sqb, gtauI, accum);
      knn64w_kernel<<<64 * NS64, 256, 0, stream>>>(Xp128, sqb, gtauI, dpartf, iparti);
      merge_kernel<NS64><<<N / 256, 256, 0, stream>>>(dpartf, iparti, idxb);
    }
    uv_kernel<<<N / 4, 256, 0, stream>>>(fin, cin, W, b, Ub, Vb);
    if (use_bn) {
      stats_kernel<<<256, 256, 0, stream>>>(Ub, Vb, idxb, accum);
      bnfin_kernel<<<1, 64, 0, stream>>>(accum, g, be, scaleb, shiftb);
    }
    apply_kernel<<<N / 4, 256, 0, stream>>>(Ub, Vb, idxb, scaleb, shiftb, use_bn, fout);
  };

  run_layer(x, 3, W1, b1, g1, be1, 1, f1);
  run_layer(f1, 64, W2, b2, nullptr, nullptr, 0, f2);
  run_layer(f2, 64, W3, b3, g3, be3, 1, f3);
  run_layer(f3, 64, W4, b4, nullptr, nullptr, 0, f4);
  pool1_kernel<<<256, 256, 0, stream>>>(f1, f2, f3, f4, n_pts, Ppart);
  head_kernel<<<64, 128, 0, stream>>>(Ppart, Wp, bp, out);
}

// Round 15
// 1249.224 us; speedup vs baseline: 1.4880x; 1.4880x over previous
//
#include <hip/hip_runtime.h>
#include <hip/hip_bf16.h>

constexpr int N = 16384;   // points
constexpr int KNN = 10;
constexpr int CF = 64;     // feature channels per edgeconv
constexpr int NS64 = 12;   // col splits for knn64 (grid 64*12 = 768 = 3 blocks/CU)
constexpr int NS3 = 12;    // col splits for knn3  (grid 64*12 = 768)

#define FBIG 1e30f

typedef __attribute__((ext_vector_type(8))) __bf16 bfv8;
typedef __attribute__((ext_vector_type(4))) float f32x4;

// ---------- top-k insert (replace-max) ----------
#define TOPK_INSERT(dval, jval)                                            \
  if ((dval) < bmax) {                                                     \
    float mv = bd[0]; int slot = 0;                                        \
    _Pragma("unroll") for (int s_ = 1; s_ < 10; ++s_)                      \
      if (bd[s_] > mv) { mv = bd[s_]; slot = s_; }                         \
    _Pragma("unroll") for (int s_ = 0; s_ < 10; ++s_)                      \
      if (slot == s_) { bd[s_] = (dval); bi[s_] = (jval); }                \
    bmax = bd[0];                                                          \
    _Pragma("unroll") for (int s_ = 1; s_ < 10; ++s_)                      \
      bmax = fmaxf(bmax, bd[s_]);                                          \
  }

__device__ inline ushort bf16_rne(float x) {
  unsigned u = __float_as_uint(x);
  return (ushort)((u + 0x7FFFu + ((u >> 16) & 1u)) >> 16);
}
__device__ inline float bf16_to_f(ushort h) { return __uint_as_float(((unsigned)h) << 16); }

// ---------- pack x (3ch) into float4 with sq norm; init gtau + accum ----------
__global__ __launch_bounds__(256) void pack3_kernel(const float* __restrict__ X,
                                                    float4* __restrict__ xp,
                                                    int* __restrict__ gtauI,
                                                    float* __restrict__ accum) {
  int i = blockIdx.x * 256 + threadIdx.x;
  float x0 = X[3 * i], x1 = X[3 * i + 1], x2 = X[3 * i + 2];
  float s = fmaf(x0, x0, fmaf(x1, x1, x2 * x2));
  xp[i] = make_float4(x0, x1, x2, s);
  gtauI[i] = 0x7F7F7F7F;  // ~3.39e38
  if (blockIdx.x == 0 && threadIdx.x < 128) accum[threadIdx.x] = 0.f;
}

// ---------- fused 64-ch prep: bf16 hi/lo split + sq norm; init gtau + accum ----------
__global__ __launch_bounds__(256) void prep128s_kernel(const float* __restrict__ X,
                                                       ushort* __restrict__ Xp,
                                                       float* __restrict__ sq,
                                                       int* __restrict__ gtauI,
                                                       float* __restrict__ accum) {
  int i = blockIdx.x * 256 + threadIdx.x;
  int n = i >> 4, k4 = (i & 15) << 2;
  float4 v = ((const float4*)X)[i];
  float vv[4] = {v.x, v.y, v.z, v.w};
  ushort h[4], lo[4];
#pragma unroll
  for (int k = 0; k < 4; ++k) {
    h[k] = bf16_rne(vv[k]);
    lo[k] = bf16_rne(vv[k] - bf16_to_f(h[k]));
  }
  ushort* row = Xp + (size_t)n * 128;
  *(ushort4*)(row + k4) = make_ushort4(h[0], h[1], h[2], h[3]);
  *(ushort4*)(row + 64 + k4) = make_ushort4(lo[0], lo[1], lo[2], lo[3]);
  float ps = fmaf(vv[0], vv[0], fmaf(vv[1], vv[1], fmaf(vv[2], vv[2], vv[3] * vv[3])));
#pragma unroll
  for (int m = 1; m < 16; m <<= 1) ps += __shfl_xor(ps, m, 16);
  if ((threadIdx.x & 15) == 0) {
    sq[n] = ps;
    gtauI[n] = 0x7F7F7F7F;
  }
  if (blockIdx.x == 0 && threadIdx.x < 128) accum[threadIdx.x] = 0.f;
}

// ---------- kNN for C=64 via bf16-split MFMA: 32-col chunks (r13-banked, 213us) ----------
// NOTE (r14): __launch_bounds__(256,4) demotes the 64-VGPR pinned A-frags -> A gets
// re-streamed from global every chunk (FETCH 2x, 374us). Keep (256,3) + fat registers.
__global__ __launch_bounds__(256, 3) void knn64w_kernel(const ushort* __restrict__ Xp,
                                                        const float* __restrict__ sq,
                                                        int* __restrict__ gtauI,
                                                        float* __restrict__ dpart,
                                                        ushort* __restrict__ ipart) {
  __shared__ float bufD[4][64 * 33];
  __shared__ ushort bufI[4][64 * 34];
  __shared__ __align__(16) float tauS[4][64];
  __shared__ int cntS[4][64];

  const int tid = threadIdx.x;
  const int w = tid >> 6, l = tid & 63, lp = l & 15, g = l >> 4;
  const int rg = blockIdx.x / NS64, cs = blockIdx.x % NS64;
  const int wbase = rg * 256 + w * 64;
  const int myrow = wbase + l;
  const int c0 = (512 * cs) / NS64, c1 = (512 * (cs + 1)) / NS64;  // 32-col chunks

  tauS[w][l] = FBIG;
  cntS[w][l] = 0;
  __builtin_amdgcn_wave_barrier();

  // A fragments: 4 row-tiles (rows wbase + rt*16 + lp, k-slice g*8)
  bfv8 aH1[4], aH2[4], aL1[4], aL2[4];
#pragma unroll
  for (int rt = 0; rt < 4; ++rt) {
    const size_t ao = (size_t)(wbase + rt * 16 + lp) * 128 + g * 8;
    aH1[rt] = *(const bfv8*)&Xp[ao];
    aH2[rt] = *(const bfv8*)&Xp[ao + 32];
    aL1[rt] = *(const bfv8*)&Xp[ao + 64];
    aL2[rt] = *(const bfv8*)&Xp[ao + 96];
  }
  float sqi[16];
#pragma unroll
  for (int rt = 0; rt < 4; ++rt)
#pragma unroll
    for (int r = 0; r < 4; ++r) sqi[rt * 4 + r] = sq[wbase + rt * 16 + g * 4 + r];

  float bd[10]; int bi[10]; float bmax = FBIG; float lastPub = FBIG;
#pragma unroll
  for (int s = 0; s < 10; ++s) { bd[s] = FBIG; bi[s] = 0x7fffffff; }
  int gt = 0x7F7F7F7F;

  for (int t = c0; t < c1; ++t) {
    const int col0 = t * 32 + lp;
    const int col1 = col0 + 16;
    const size_t bo0 = (size_t)col0 * 128 + g * 8;
    bfv8 p0 = *(const bfv8*)&Xp[bo0];
    bfv8 p1 = *(const bfv8*)&Xp[bo0 + 32];
    bfv8 p2 = *(const bfv8*)&Xp[bo0 + 64];
    bfv8 p3 = *(const bfv8*)&Xp[bo0 + 96];
    const size_t bo1 = (size_t)col1 * 128 + g * 8;
    bfv8 q0 = *(const bfv8*)&Xp[bo1];
    bfv8 q1 = *(const bfv8*)&Xp[bo1 + 32];
    bfv8 q2 = *(const bfv8*)&Xp[bo1 + 64];
    bfv8 q3 = *(const bfv8*)&Xp[bo1 + 96];
    float sj0 = sq[col0];
    float sj1 = sq[col1];
    int gtn = gtauI[myrow];

    __builtin_amdgcn_wave_barrier();
    {  // drain prev chunk: every lane owns row l
      const int c = cntS[w][l];
      if (c) {
        const float* bD = &bufD[w][l * 33];
        const ushort* bI = &bufI[w][l * 34];
#pragma unroll 1
        for (int j = 0; j < c; ++j) {
          float d = bD[j];
          int ii = (int)bI[j];
          TOPK_INSERT(d, ii);
        }
        cntS[w][l] = 0;
      }
      tauS[w][l] = fminf(bmax, __int_as_float(gt));
      if (bmax < lastPub) {  // publish only on improvement
        atomicMin(&gtauI[myrow], __float_as_int(bmax));
        lastPub = bmax;
      }
    }
    __builtin_amdgcn_wave_barrier();
    gt = gtn;

#pragma unroll
    for (int rt = 0; rt < 4; ++rt) {
      f32x4 taur = *(const f32x4*)&tauS[w][rt * 16 + g * 4];
      f32x4 acc0 = {0.f, 0.f, 0.f, 0.f};
      acc0 = __builtin_amdgcn_mfma_f32_16x16x32_bf16(aH1[rt], p0, acc0, 0, 0, 0);
      acc0 = __builtin_amdgcn_mfma_f32_16x16x32_bf16(aH2[rt], p1, acc0, 0, 0, 0);
      acc0 = __builtin_amdgcn_mfma_f32_16x16x32_bf16(aH1[rt], p2, acc0, 0, 0, 0);
      acc0 = __builtin_amdgcn_mfma_f32_16x16x32_bf16(aH2[rt], p3, acc0, 0, 0, 0);
      acc0 = __builtin_amdgcn_mfma_f32_16x16x32_bf16(aL1[rt], p0, acc0, 0, 0, 0);
      acc0 = __builtin_amdgcn_mfma_f32_16x16x32_bf16(aL2[rt], p1, acc0, 0, 0, 0);
      f32x4 acc1 = {0.f, 0.f, 0.f, 0.f};
      acc1 = __builtin_amdgcn_mfma_f32_16x16x32_bf16(aH1[rt], q0, acc1, 0, 0, 0);
      acc1 = __builtin_amdgcn_mfma_f32_16x16x32_bf16(aH2[rt], q1, acc1, 0, 0, 0);
      acc1 = __builtin_amdgcn_mfma_f32_16x16x32_bf16(aH1[rt], q2, acc1, 0, 0, 0);
      acc1 = __builtin_amdgcn_mfma_f32_16x16x32_bf16(aH2[rt], q3, acc1, 0, 0, 0);
      acc1 = __builtin_amdgcn_mfma_f32_16x16x32_bf16(aL1[rt], q0, acc1, 0, 0, 0);
      acc1 = __builtin_amdgcn_mfma_f32_16x16x32_bf16(aL2[rt], q1, acc1, 0, 0, 0);
#pragma unroll
      for (int r = 0; r < 4; ++r) {
        const int rloc = rt * 16 + g * 4 + r;
        float d0 = fmaf(-2.f, acc0[r], sqi[rt * 4 + r] + sj0);
        if (d0 < taur[r]) {
          int pos = atomicAdd(&cntS[w][rloc], 1);
          bufD[w][rloc * 33 + pos] = d0;
          bufI[w][rloc * 34 + pos] = (ushort)col0;
        }
        float d1 = fmaf(-2.f, acc1[r], sqi[rt * 4 + r] + sj1);
        if (d1 < taur[r]) {
          int pos = atomicAdd(&cntS[w][rloc], 1);
          bufD[w][rloc * 33 + pos] = d1;
          bufI[w][rloc * 34 + pos] = (ushort)col1;
        }
      }
    }
  }

  __builtin_amdgcn_wave_barrier();
  {  // final drain
    const int c = cntS[w][l];
    const float* bD = &bufD[w][l * 33];
    const ushort* bI = &bufI[w][l * 34];
#pragma unroll 1
    for (int j = 0; j < c; ++j) {
      float d = bD[j];
      int ii = (int)bI[j];
      TOPK_INSERT(d, ii);
    }
  }
  float* dp = dpart + ((size_t)cs * N + myrow) * 10;
  ushort* ip = ipart + ((size_t)cs * N + myrow) * 10;
#pragma unroll
  for (int s = 0; s < 10; ++s) { dp[s] = bd[s]; ip[s] = (ushort)bi[s]; }
}

// ---------- kNN for C=3, exact fp32 (cancellation-sensitive: keep fp32!) ----------
// r11-measured version: 64 rows/wave, 16-col chunks, global tau.
__global__ __launch_bounds__(256, 3) void knn3g_kernel(const float4* __restrict__ xp,
                                                       int* __restrict__ gtauI,
                                                       float* __restrict__ dpart,
                                                       ushort* __restrict__ ipart) {
  __shared__ float bufD[4][64 * 17];
  __shared__ ushort bufI[4][64 * 18];
  __shared__ __align__(16) float tauS[4][64];
  __shared__ int cntS[4][64];

  const int tid = threadIdx.x;
  const int w = tid >> 6, l = tid & 63, lp = l & 15, g = l >> 4;
  const int rg = blockIdx.x / NS3, cs = blockIdx.x % NS3;
  const int wbase = rg * 256 + w * 64;
  const int myrow = wbase + l;
  const int c0 = (1024 * cs) / NS3, c1 = (1024 * (cs + 1)) / NS3;

  tauS[w][l] = FBIG;
  cntS[w][l] = 0;
  __builtin_amdgcn_wave_barrier();

  // 16 pinned row float4s: rows wbase + rt*16 + g*4 + r
  float4 rw[16];
#pragma unroll
  for (int rt = 0; rt < 4; ++rt)
#pragma unroll
    for (int r = 0; r < 4; ++r) rw[rt * 4 + r] = xp[wbase + rt * 16 + g * 4 + r];

  float bd[10]; int bi[10]; float bmax = FBIG; float lastPub = FBIG;
#pragma unroll
  for (int s = 0; s < 10; ++s) { bd[s] = FBIG; bi[s] = 0x7fffffff; }
  int gt = 0x7F7F7F7F;

  for (int t = c0; t < c1; ++t) {
    const int bcol = t * 16 + lp;
    const float4 oc = xp[bcol];
    int gtn = gtauI[myrow];

    __builtin_amdgcn_wave_barrier();
    {  // drain prev chunk
      const int c = cntS[w][l];
      if (c) {
        const float* bD = &bufD[w][l * 17];
        const ushort* bI = &bufI[w][l * 18];
#pragma unroll 1
        for (int j = 0; j < c; ++j) {
          float d = bD[j];
          int ii = (int)bI[j];
          TOPK_INSERT(d, ii);
        }
        cntS[w][l] = 0;
      }
      tauS[w][l] = fminf(bmax, __int_as_float(gt));
      if (bmax < lastPub) {
        atomicMin(&gtauI[myrow], __float_as_int(bmax));
        lastPub = bmax;
      }
    }
    __builtin_amdgcn_wave_barrier();
    gt = gtn;

#pragma unroll
    for (int rt = 0; rt < 4; ++rt) {
      f32x4 taur = *(const f32x4*)&tauS[w][rt * 16 + g * 4];
#pragma unroll
      for (int r = 0; r < 4; ++r) {
        const float4 m = rw[rt * 4 + r];
        float dot = fmaf(m.x, oc.x, fmaf(m.y, oc.y, m.z * oc.z));
        float d = fmaf(-2.f, dot, m.w + oc.w);  // same chain as validated knn3
        if (d < taur[r]) {
          int rloc = rt * 16 + g * 4 + r;
          int pos = atomicAdd(&cntS[w][rloc], 1);
          bufD[w][rloc * 17 + pos] = d;
          bufI[w][rloc * 18 + pos] = (ushort)bcol;
        }
      }
    }
  }

  __builtin_amdgcn_wave_barrier();
  {  // final drain
    const int c = cntS[w][l];
    const float* bD = &bufD[w][l * 17];
    const ushort* bI = &bufI[w][l * 18];
#pragma unroll 1
    for (int j = 0; j < c; ++j) {
      float d = bD[j];
      int ii = (int)bI[j];
      TOPK_INSERT(d, ii);
    }
  }
  float* dp = dpart + ((size_t)cs * N + myrow) * 10;
  ushort* ip = ipart + ((size_t)cs * N + myrow) * 10;
#pragma unroll
  for (int s = 0; s < 10; ++s) { dp[s] = bd[s]; ip[s] = (ushort)bi[s]; }
}

// ---------- merge S partial top-10 lists per row (r11-measured version) ----------
template <int S>
__global__ __launch_bounds__(256) void merge_kernel(const float* __restrict__ dpart,
                                                    const ushort* __restrict__ ipart,
                                                    ushort* __restrict__ idx_out) {
  const int row = blockIdx.x * 256 + threadIdx.x;
  float d[S * 10]; int id_[S * 10];
#pragma unroll
  for (int p = 0; p < S; ++p)
#pragma unroll
    for (int s = 0; s < 10; ++s) {
      d[p * 10 + s] = dpart[((size_t)p * N + row) * 10 + s];
      id_[p * 10 + s] = (int)ipart[((size_t)p * N + row) * 10 + s];
    }
#pragma unroll
  for (int t = 0; t < 10; ++t) {
    float dm = d[0]; int im = id_[0]; int slot = 0;
#pragma unroll
    for (int e = 1; e < S * 10; ++e) {
      bool better = (d[e] < dm) || (d[e] == dm && id_[e] < im);
      if (better) { dm = d[e]; im = id_[e]; slot = e; }
    }
    idx_out[(size_t)row * 10 + t] = (ushort)im;
#pragma unroll
    for (int e = 0; e < S * 10; ++e)
      if (e == slot) d[e] = FBIG;
  }
}

// ---------- u = x*W_bot ; v = x*(W_top - W_bot) + b  (W staged in LDS) ----------
__global__ __launch_bounds__(256) void uv_kernel(const float* __restrict__ Xf, int CIN,
                                                 const float* __restrict__ W,
                                                 const float* __restrict__ bias,
                                                 float* __restrict__ U, float* __restrict__ V) {
  __shared__ float Ws[8192];  // 2*CIN*64 floats, max 32KB at CIN=64
  int tid = threadIdx.x;
  int c = tid & 63, p = tid >> 6;
  int n = blockIdx.x * 4 + p;
  const int tot = CIN * 128;
  for (int i = tid; i < tot; i += 256) Ws[i] = W[i];
  __syncthreads();
  const float* xr = Xf + (size_t)n * CIN;
  float vt = 0.f, vb = 0.f;
  for (int m = 0; m < CIN; ++m) {
    float xm = xr[m];
    vt = fmaf(xm, Ws[m * 64 + c], vt);
    vb = fmaf(xm, Ws[(CIN + m) * 64 + c], vb);
  }
  U[(size_t)n * 64 + c] = vb;
  V[(size_t)n * 64 + c] = vt - vb + bias[c];
}

// ---------- BN batch stats ----------
__global__ __launch_bounds__(256) void stats_kernel(const float* __restrict__ U,
                                                    const float* __restrict__ V,
                                                    const ushort* __restrict__ idx,
                                                    float* __restrict__ accum) {
  int tid = threadIdx.x;
  int c = tid & 63, p = tid >> 6;
  int base = blockIdx.x * 64;  // 256 blocks x 64 points
  float s = 0.f, s2 = 0.f;
  for (int ch = 0; ch < 16; ++ch) {
    int n = base + ch * 4 + p;
    float vn = V[(size_t)n * 64 + c];
    const ushort* in_ = idx + (size_t)n * 10;
#pragma unroll
    for (int k = 0; k < 10; ++k) {
      float h = vn + U[(size_t)in_[k] * 64 + c];
      s += h;
      s2 = fmaf(h, h, s2);
    }
  }
  __shared__ float red[256], red2[256];
  red[tid] = s; red2[tid] = s2;
  __syncthreads();
  if (tid < 64) {
    float ts = red[tid] + red[64 + tid] + red[128 + tid] + red[192 + tid];
    float t2 = red2[tid] + red2[64 + tid] + red2[128 + tid] + red2[192 + tid];
    atomicAdd(&accum[tid], ts);
    atomicAdd(&accum[64 + tid], t2);
  }
}

__global__ void bnfin_kernel(const float* __restrict__ accum,
                             const float* __restrict__ gamma,
                             const float* __restrict__ beta,
                             float* __restrict__ scale, float* __restrict__ shift) {
  int c = threadIdx.x;  // 64
  float inv = 1.f / (float)(N * KNN);
  float mu = accum[c] * inv;
  float var = accum[64 + c] * inv - mu * mu;
  float sc = gamma[c] * rsqrtf(var + 1e-5f);
  scale[c] = sc;
  shift[c] = fmaf(-mu, sc, beta[c]);
}

// ---------- apply (BN) + ReLU + max over k ----------
__global__ __launch_bounds__(256) void apply_kernel(const float* __restrict__ U,
                                                    const float* __restrict__ V,
                                                    const ushort* __restrict__ idx,
                                                    const float* __restrict__ scale,
                                                    const float* __restrict__ shift,
                                                    int use_bn, float* __restrict__ Fout) {
  int tid = threadIdx.x;
  int c = tid & 63, p = tid >> 6;
  int n = blockIdx.x * 4 + p;
  float sc = use_bn ? scale[c] : 1.f;
  float sh = use_bn ? shift[c] : 0.f;
  float vn = V[(size_t)n * 64 + c];
  const ushort* in_ = idx + (size_t)n * 10;
  float m = 0.f;
#pragma unroll
  for (int k = 0; k < 10; ++k) {
    float h = vn + U[(size_t)in_[k] * 64 + c];
    m = fmaxf(m, fmaf(h, sc, sh));
  }
  Fout[(size_t)n * 64 + c] = m;
}

// ---------- segment max pooling, stage 1 (stage 2 fused into head) ----------
__global__ __launch_bounds__(256) void pool1_kernel(const float* __restrict__ f1,
                                                    const float* __restrict__ f2,
                                                    const float* __restrict__ f3,
                                                    const float* __restrict__ f4,
                                                    const int* __restrict__ n_pts,
                                                    float* __restrict__ Pp) {
  int b = blockIdx.x >> 2;
  int q = blockIdx.x & 3;
  int c = threadIdx.x;
  int off = 0;
  for (int i = 0; i < b; ++i) off += n_pts[i];
  int cnt_ = n_pts[b];
  int s0 = off + (cnt_ * q) / 4;
  int s1 = off + (cnt_ * (q + 1)) / 4;
  const float* f = (c < 64) ? f1 : (c < 128) ? f2 : (c < 192) ? f3 : f4;
  int ch = c & 63;
  float m = -3.4e38f;
  for (int t = s0; t < s1; ++t) m = fmaxf(m, f[(size_t)t * 64 + ch]);
  Pp[((size_t)q * 64 + b) * 256 + c] = m;
}

// ---------- head: 4-way pool max + tanh(P@Wp + bp) + L2 normalize ----------
__global__ __launch_bounds__(128) void head_kernel(const float* __restrict__ Pp,
                                                   const float* __restrict__ Wp,
                                                   const float* __restrict__ bp,
                                                   float* __restrict__ out) {
  int b = blockIdx.x;
  int c = threadIdx.x;
  __shared__ float ps[256];
#pragma unroll
  for (int j = 0; j < 2; ++j) {
    int cc = c + j * 128;
    float m = Pp[(size_t)b * 256 + cc];
#pragma unroll
    for (int q = 1; q < 4; ++q) m = fmaxf(m, Pp[((size_t)q * 64 + b) * 256 + cc]);
    ps[cc] = m;
  }
  __syncthreads();
  float acc = bp[c];
  for (int m = 0; m < 256; ++m) acc = fmaf(ps[m], Wp[m * 128 + c], acc);
  float t = tanhf(acc);
  __shared__ float red[128];
  red[c] = t * t;
  __syncthreads();
  for (int s = 64; s > 0; s >>= 1) {
    if (c < s) red[c] += red[c + s];
    __syncthreads();
  }
  float nrm = sqrtf(red[0]);
  out[b * 128 + c] = t / (nrm + 1e-9f);
}

extern "C" void kernel_launch(void* const* d_in, const int* in_sizes, int n_in,
                              void* d_out, int out_size, void* d_ws, size_t ws_size,
                              hipStream_t stream) {
  const float* x = (const float*)d_in[0];
  const int* n_pts = (const int*)d_in[1];
  const float* W1 = (const float*)d_in[2];
  const float* b1 = (const float*)d_in[3];
  const float* g1 = (const float*)d_in[4];
  const float* be1 = (const float*)d_in[5];
  const float* W2 = (const float*)d_in[6];
  const float* b2 = (const float*)d_in[7];
  const float* W3 = (const float*)d_in[8];
  const float* b3 = (const float*)d_in[9];
  const float* g3 = (const float*)d_in[10];
  const float* be3 = (const float*)d_in[11];
  const float* W4 = (const float*)d_in[12];
  const float* b4 = (const float*)d_in[13];
  const float* Wp = (const float*)d_in[14];
  const float* bp = (const float*)d_in[15];
  float* out = (float*)d_out;

  char* w = (char*)d_ws;
  auto alloc = [&](size_t bytes) {
    char* p = w;
    w += (bytes + 255) & ~(size_t)255;
    return p;
  };
  const size_t FS = (size_t)N * 64 * 4;
  float* f1 = (float*)alloc(FS);
  float* f2 = (float*)alloc(FS);
  float* f3 = (float*)alloc(FS);
  float* f4 = (float*)alloc(FS);
  float* Ub = (float*)alloc(FS);                              // overlaid: Xp128
  float* dpartf = (float*)alloc((size_t)NS64 * N * 10 * 4);   // 7.86 MB
  ushort* iparti = (ushort*)alloc((size_t)NS64 * N * 10 * 2); // 3.93 MB
  float4* xp = (float4*)alloc((size_t)N * 16);
  float* sqb = (float*)alloc((size_t)N * 4);
  int* gtauI = (int*)alloc((size_t)N * 4);
  ushort* idxb = (ushort*)alloc((size_t)N * 10 * 2);
  float* accum = (float*)alloc(512);
  float* scaleb = (float*)alloc(256);
  float* shiftb = (float*)alloc(256);
  float* Ppart = (float*)alloc((size_t)4 * 64 * 256 * 4);
  ushort* Xp128 = (ushort*)Ub;
  // V overlays dpart's first 4 MB: dpart consumed by merge BEFORE uv writes V;
  // V consumed by stats/apply BEFORE the next layer's knn writes dpart.
  float* Vb = dpartf;
  (void)ws_size; (void)n_in; (void)in_sizes; (void)out_size;

  auto run_layer = [&](const float* fin, int cin, const float* W, const float* b,
                       const float* g, const float* be, int use_bn, float* fout) {
    if (cin == 3) {
      pack3_kernel<<<N / 256, 256, 0, stream>>>(fin, xp, gtauI, accum);
      knn3g_kernel<<<64 * NS3, 256, 0, stream>>>(xp, gtauI, dpartf, iparti);
      merge_kernel<NS3><<<N / 256, 256, 0, stream>>>(dpartf, iparti, idxb);
    } else {
      prep128s_kernel<<<N * 64 / 4 / 256, 256, 0, stream>>>(fin, Xp128, sqb, gtauI, accum);
      knn64w_kernel<<<64 * NS64, 256, 0, stream>>>(Xp128, sqb, gtauI, dpartf, iparti);
      merge_kernel<NS64><<<N / 256, 256, 0, stream>>>(dpartf, iparti, idxb);
    }
    uv_kernel<<<N / 4, 256, 0, stream>>>(fin, cin, W, b, Ub, Vb);
    if (use_bn) {
      stats_kernel<<<256, 256, 0, stream>>>(Ub, Vb, idxb, accum);
      bnfin_kernel<<<1, 64, 0, stream>>>(accum, g, be, scaleb, shiftb);
    }
    apply_kernel<<<N / 4, 256, 0, stream>>>(Ub, Vb, idxb, scaleb, shiftb, use_bn, fout);
  };

  run_layer(x, 3, W1, b1, g1, be1, 1, f1);
  run_layer(f1, 64, W2, b2, nullptr, nullptr, 0, f2);
  run_layer(f2, 64, W3, b3, g3, be3, 1, f3);
  run_layer(f3, 64, W4, b4, nullptr, nullptr, 0, f4);
  pool1_kernel<<<256, 256, 0, stream>>>(f1, f2, f3, f4, n_pts, Ppart);
  head_kernel<<<64, 128, 0, stream>>>(Ppart, Wp, bp, out);
}

// Round 16
// 1221.444 us; speedup vs baseline: 1.5218x; 1.0227x over previous
//
#include <hip/hip_runtime.h>
#include <hip/hip_bf16.h>

constexpr int N = 16384;   // points
constexpr int KNN = 10;
constexpr int CF = 64;     // feature channels per edgeconv
constexpr int NS64 = 12;   // col splits for knn64 (grid 64*12 = 768 = 3 blocks/CU)
constexpr int NS3 = 12;    // col splits for knn3  (grid 64*12 = 768)

#define FBIG 1e30f

typedef __attribute__((ext_vector_type(8))) __bf16 bfv8;
typedef __attribute__((ext_vector_type(4))) float f32x4;

// ---------- top-k insert (replace-max) ----------
#define TOPK_INSERT(dval, jval)                                            \
  if ((dval) < bmax) {                                                     \
    float mv = bd[0]; int slot = 0;                                        \
    _Pragma("unroll") for (int s_ = 1; s_ < 10; ++s_)                      \
      if (bd[s_] > mv) { mv = bd[s_]; slot = s_; }                         \
    _Pragma("unroll") for (int s_ = 0; s_ < 10; ++s_)                      \
      if (slot == s_) { bd[s_] = (dval); bi[s_] = (jval); }                \
    bmax = bd[0];                                                          \
    _Pragma("unroll") for (int s_ = 1; s_ < 10; ++s_)                      \
      bmax = fmaxf(bmax, bd[s_]);                                          \
  }

__device__ inline ushort bf16_rne(float x) {
  unsigned u = __float_as_uint(x);
  return (ushort)((u + 0x7FFFu + ((u >> 16) & 1u)) >> 16);
}
__device__ inline float bf16_to_f(ushort h) { return __uint_as_float(((unsigned)h) << 16); }

// ---------- pack x (3ch) into float4 with sq norm; init gtau + accum ----------
__global__ __launch_bounds__(256) void pack3_kernel(const float* __restrict__ X,
                                                    float4* __restrict__ xp,
                                                    int* __restrict__ gtauI,
                                                    float* __restrict__ accum) {
  int i = blockIdx.x * 256 + threadIdx.x;
  float x0 = X[3 * i], x1 = X[3 * i + 1], x2 = X[3 * i + 2];
  float s = fmaf(x0, x0, fmaf(x1, x1, x2 * x2));
  xp[i] = make_float4(x0, x1, x2, s);
  gtauI[i] = 0x7F7F7F7F;  // ~3.39e38
  if (blockIdx.x == 0 && threadIdx.x < 128) accum[threadIdx.x] = 0.f;
}

// ---------- fused 64-ch prep: bf16 hi/lo split + sq norm; init gtau + accum ----------
__global__ __launch_bounds__(256) void prep128s_kernel(const float* __restrict__ X,
                                                       ushort* __restrict__ Xp,
                                                       float* __restrict__ sq,
                                                       int* __restrict__ gtauI,
                                                       float* __restrict__ accum) {
  int i = blockIdx.x * 256 + threadIdx.x;
  int n = i >> 4, k4 = (i & 15) << 2;
  float4 v = ((const float4*)X)[i];
  float vv[4] = {v.x, v.y, v.z, v.w};
  ushort h[4], lo[4];
#pragma unroll
  for (int k = 0; k < 4; ++k) {
    h[k] = bf16_rne(vv[k]);
    lo[k] = bf16_rne(vv[k] - bf16_to_f(h[k]));
  }
  ushort* row = Xp + (size_t)n * 128;
  *(ushort4*)(row + k4) = make_ushort4(h[0], h[1], h[2], h[3]);
  *(ushort4*)(row + 64 + k4) = make_ushort4(lo[0], lo[1], lo[2], lo[3]);
  float ps = fmaf(vv[0], vv[0], fmaf(vv[1], vv[1], fmaf(vv[2], vv[2], vv[3] * vv[3])));
#pragma unroll
  for (int m = 1; m < 16; m <<= 1) ps += __shfl_xor(ps, m, 16);
  if ((threadIdx.x & 15) == 0) {
    sq[n] = ps;
    gtauI[n] = 0x7F7F7F7F;
  }
  if (blockIdx.x == 0 && threadIdx.x < 128) accum[threadIdx.x] = 0.f;
}

// ---------- kNN for C=64 via bf16-split MFMA: 32-col chunks (r13-banked, 213us) ----------
// NOTE (r14): __launch_bounds__(256,4) demotes the 64-VGPR pinned A-frags -> A gets
// re-streamed from global every chunk (FETCH 2x, 374us). Keep (256,3) + fat registers.
__global__ __launch_bounds__(256, 3) void knn64w_kernel(const ushort* __restrict__ Xp,
                                                        const float* __restrict__ sq,
                                                        int* __restrict__ gtauI,
                                                        float* __restrict__ dpart,
                                                        ushort* __restrict__ ipart) {
  __shared__ float bufD[4][64 * 33];
  __shared__ ushort bufI[4][64 * 34];
  __shared__ __align__(16) float tauS[4][64];
  __shared__ int cntS[4][64];

  const int tid = threadIdx.x;
  const int w = tid >> 6, l = tid & 63, lp = l & 15, g = l >> 4;
  const int rg = blockIdx.x / NS64, cs = blockIdx.x % NS64;
  const int wbase = rg * 256 + w * 64;
  const int myrow = wbase + l;
  const int c0 = (512 * cs) / NS64, c1 = (512 * (cs + 1)) / NS64;  // 32-col chunks

  tauS[w][l] = FBIG;
  cntS[w][l] = 0;
  __builtin_amdgcn_wave_barrier();

  // A fragments: 4 row-tiles (rows wbase + rt*16 + lp, k-slice g*8)
  bfv8 aH1[4], aH2[4], aL1[4], aL2[4];
#pragma unroll
  for (int rt = 0; rt < 4; ++rt) {
    const size_t ao = (size_t)(wbase + rt * 16 + lp) * 128 + g * 8;
    aH1[rt] = *(const bfv8*)&Xp[ao];
    aH2[rt] = *(const bfv8*)&Xp[ao + 32];
    aL1[rt] = *(const bfv8*)&Xp[ao + 64];
    aL2[rt] = *(const bfv8*)&Xp[ao + 96];
  }
  float sqi[16];
#pragma unroll
  for (int rt = 0; rt < 4; ++rt)
#pragma unroll
    for (int r = 0; r < 4; ++r) sqi[rt * 4 + r] = sq[wbase + rt * 16 + g * 4 + r];

  float bd[10]; int bi[10]; float bmax = FBIG; float lastPub = FBIG;
#pragma unroll
  for (int s = 0; s < 10; ++s) { bd[s] = FBIG; bi[s] = 0x7fffffff; }
  int gt = 0x7F7F7F7F;

  for (int t = c0; t < c1; ++t) {
    const int col0 = t * 32 + lp;
    const int col1 = col0 + 16;
    const size_t bo0 = (size_t)col0 * 128 + g * 8;
    bfv8 p0 = *(const bfv8*)&Xp[bo0];
    bfv8 p1 = *(const bfv8*)&Xp[bo0 + 32];
    bfv8 p2 = *(const bfv8*)&Xp[bo0 + 64];
    bfv8 p3 = *(const bfv8*)&Xp[bo0 + 96];
    const size_t bo1 = (size_t)col1 * 128 + g * 8;
    bfv8 q0 = *(const bfv8*)&Xp[bo1];
    bfv8 q1 = *(const bfv8*)&Xp[bo1 + 32];
    bfv8 q2 = *(const bfv8*)&Xp[bo1 + 64];
    bfv8 q3 = *(const bfv8*)&Xp[bo1 + 96];
    float sj0 = sq[col0];
    float sj1 = sq[col1];
    int gtn = gtauI[myrow];

    __builtin_amdgcn_wave_barrier();
    {  // drain prev chunk: every lane owns row l
      const int c = cntS[w][l];
      if (c) {
        const float* bD = &bufD[w][l * 33];
        const ushort* bI = &bufI[w][l * 34];
#pragma unroll 1
        for (int j = 0; j < c; ++j) {
          float d = bD[j];
          int ii = (int)bI[j];
          TOPK_INSERT(d, ii);
        }
        cntS[w][l] = 0;
      }
      tauS[w][l] = fminf(bmax, __int_as_float(gt));
      if (bmax < lastPub) {  // publish only on improvement
        atomicMin(&gtauI[myrow], __float_as_int(bmax));
        lastPub = bmax;
      }
    }
    __builtin_amdgcn_wave_barrier();
    gt = gtn;

#pragma unroll
    for (int rt = 0; rt < 4; ++rt) {
      f32x4 taur = *(const f32x4*)&tauS[w][rt * 16 + g * 4];
      f32x4 acc0 = {0.f, 0.f, 0.f, 0.f};
      acc0 = __builtin_amdgcn_mfma_f32_16x16x32_bf16(aH1[rt], p0, acc0, 0, 0, 0);
      acc0 = __builtin_amdgcn_mfma_f32_16x16x32_bf16(aH2[rt], p1, acc0, 0, 0, 0);
      acc0 = __builtin_amdgcn_mfma_f32_16x16x32_bf16(aH1[rt], p2, acc0, 0, 0, 0);
      acc0 = __builtin_amdgcn_mfma_f32_16x16x32_bf16(aH2[rt], p3, acc0, 0, 0, 0);
      acc0 = __builtin_amdgcn_mfma_f32_16x16x32_bf16(aL1[rt], p0, acc0, 0, 0, 0);
      acc0 = __builtin_amdgcn_mfma_f32_16x16x32_bf16(aL2[rt], p1, acc0, 0, 0, 0);
      f32x4 acc1 = {0.f, 0.f, 0.f, 0.f};
      acc1 = __builtin_amdgcn_mfma_f32_16x16x32_bf16(aH1[rt], q0, acc1, 0, 0, 0);
      acc1 = __builtin_amdgcn_mfma_f32_16x16x32_bf16(aH2[rt], q1, acc1, 0, 0, 0);
      acc1 = __builtin_amdgcn_mfma_f32_16x16x32_bf16(aH1[rt], q2, acc1, 0, 0, 0);
      acc1 = __builtin_amdgcn_mfma_f32_16x16x32_bf16(aH2[rt], q3, acc1, 0, 0, 0);
      acc1 = __builtin_amdgcn_mfma_f32_16x16x32_bf16(aL1[rt], q0, acc1, 0, 0, 0);
      acc1 = __builtin_amdgcn_mfma_f32_16x16x32_bf16(aL2[rt], q1, acc1, 0, 0, 0);
#pragma unroll
      for (int r = 0; r < 4; ++r) {
        const int rloc = rt * 16 + g * 4 + r;
        float d0 = fmaf(-2.f, acc0[r], sqi[rt * 4 + r] + sj0);
        if (d0 < taur[r]) {
          int pos = atomicAdd(&cntS[w][rloc], 1);
          bufD[w][rloc * 33 + pos] = d0;
          bufI[w][rloc * 34 + pos] = (ushort)col0;
        }
        float d1 = fmaf(-2.f, acc1[r], sqi[rt * 4 + r] + sj1);
        if (d1 < taur[r]) {
          int pos = atomicAdd(&cntS[w][rloc], 1);
          bufD[w][rloc * 33 + pos] = d1;
          bufI[w][rloc * 34 + pos] = (ushort)col1;
        }
      }
    }
  }

  __builtin_amdgcn_wave_barrier();
  {  // final drain
    const int c = cntS[w][l];
    const float* bD = &bufD[w][l * 33];
    const ushort* bI = &bufI[w][l * 34];
#pragma unroll 1
    for (int j = 0; j < c; ++j) {
      float d = bD[j];
      int ii = (int)bI[j];
      TOPK_INSERT(d, ii);
    }
  }
  float* dp = dpart + ((size_t)cs * N + myrow) * 10;
  ushort* ip = ipart + ((size_t)cs * N + myrow) * 10;
#pragma unroll
  for (int s = 0; s < 10; ++s) { dp[s] = bd[s]; ip[s] = (ushort)bi[s]; }
}

// ---------- kNN for C=3, exact fp32 (cancellation-sensitive: keep fp32!) ----------
// 32-col chunks (same amortization as banked knn64w-32col); global tau.
__global__ __launch_bounds__(256, 3) void knn3g_kernel(const float4* __restrict__ xp,
                                                       int* __restrict__ gtauI,
                                                       float* __restrict__ dpart,
                                                       ushort* __restrict__ ipart) {
  __shared__ float bufD[4][64 * 33];
  __shared__ ushort bufI[4][64 * 34];
  __shared__ __align__(16) float tauS[4][64];
  __shared__ int cntS[4][64];

  const int tid = threadIdx.x;
  const int w = tid >> 6, l = tid & 63, lp = l & 15, g = l >> 4;
  const int rg = blockIdx.x / NS3, cs = blockIdx.x % NS3;
  const int wbase = rg * 256 + w * 64;
  const int myrow = wbase + l;
  const int c0 = (512 * cs) / NS3, c1 = (512 * (cs + 1)) / NS3;  // 32-col chunks

  tauS[w][l] = FBIG;
  cntS[w][l] = 0;
  __builtin_amdgcn_wave_barrier();

  float4 rw[16];
#pragma unroll
  for (int rt = 0; rt < 4; ++rt)
#pragma unroll
    for (int r = 0; r < 4; ++r) rw[rt * 4 + r] = xp[wbase + rt * 16 + g * 4 + r];

  float bd[10]; int bi[10]; float bmax = FBIG; float lastPub = FBIG;
#pragma unroll
  for (int s = 0; s < 10; ++s) { bd[s] = FBIG; bi[s] = 0x7fffffff; }
  int gt = 0x7F7F7F7F;

  for (int t = c0; t < c1; ++t) {
    const int col0 = t * 32 + lp;
    const int col1 = col0 + 16;
    const float4 oc0 = xp[col0];
    const float4 oc1 = xp[col1];
    int gtn = gtauI[myrow];

    __builtin_amdgcn_wave_barrier();
    {  // drain prev chunk
      const int c = cntS[w][l];
      if (c) {
        const float* bD = &bufD[w][l * 33];
        const ushort* bI = &bufI[w][l * 34];
#pragma unroll 1
        for (int j = 0; j < c; ++j) {
          float d = bD[j];
          int ii = (int)bI[j];
          TOPK_INSERT(d, ii);
        }
        cntS[w][l] = 0;
      }
      tauS[w][l] = fminf(bmax, __int_as_float(gt));
      if (bmax < lastPub) {
        atomicMin(&gtauI[myrow], __float_as_int(bmax));
        lastPub = bmax;
      }
    }
    __builtin_amdgcn_wave_barrier();
    gt = gtn;

#pragma unroll
    for (int rt = 0; rt < 4; ++rt) {
      f32x4 taur = *(const f32x4*)&tauS[w][rt * 16 + g * 4];
#pragma unroll
      for (int r = 0; r < 4; ++r) {
        const float4 m = rw[rt * 4 + r];
        const int rloc = rt * 16 + g * 4 + r;
        float dot0 = fmaf(m.x, oc0.x, fmaf(m.y, oc0.y, m.z * oc0.z));
        float d0 = fmaf(-2.f, dot0, m.w + oc0.w);  // same chain as validated knn3
        if (d0 < taur[r]) {
          int pos = atomicAdd(&cntS[w][rloc], 1);
          bufD[w][rloc * 33 + pos] = d0;
          bufI[w][rloc * 34 + pos] = (ushort)col0;
        }
        float dot1 = fmaf(m.x, oc1.x, fmaf(m.y, oc1.y, m.z * oc1.z));
        float d1 = fmaf(-2.f, dot1, m.w + oc1.w);
        if (d1 < taur[r]) {
          int pos = atomicAdd(&cntS[w][rloc], 1);
          bufD[w][rloc * 33 + pos] = d1;
          bufI[w][rloc * 34 + pos] = (ushort)col1;
        }
      }
    }
  }

  __builtin_amdgcn_wave_barrier();
  {  // final drain
    const int c = cntS[w][l];
    const float* bD = &bufD[w][l * 33];
    const ushort* bI = &bufI[w][l * 34];
#pragma unroll 1
    for (int j = 0; j < c; ++j) {
      float d = bD[j];
      int ii = (int)bI[j];
      TOPK_INSERT(d, ii);
    }
  }
  float* dp = dpart + ((size_t)cs * N + myrow) * 10;
  ushort* ip = ipart + ((size_t)cs * N + myrow) * 10;
#pragma unroll
  for (int s = 0; s < 10; ++s) { dp[s] = bd[s]; ip[s] = (ushort)bi[s]; }
}

// ---------- merge S partial top-10 lists per row (r11-measured version) ----------
template <int S>
__global__ __launch_bounds__(256) void merge_kernel(const float* __restrict__ dpart,
                                                    const ushort* __restrict__ ipart,
                                                    ushort* __restrict__ idx_out) {
  const int row = blockIdx.x * 256 + threadIdx.x;
  float d[S * 10]; int id_[S * 10];
#pragma unroll
  for (int p = 0; p < S; ++p)
#pragma unroll
    for (int s = 0; s < 10; ++s) {
      d[p * 10 + s] = dpart[((size_t)p * N + row) * 10 + s];
      id_[p * 10 + s] = (int)ipart[((size_t)p * N + row) * 10 + s];
    }
#pragma unroll
  for (int t = 0; t < 10; ++t) {
    float dm = d[0]; int im = id_[0]; int slot = 0;
#pragma unroll
    for (int e = 1; e < S * 10; ++e) {
      bool better = (d[e] < dm) || (d[e] == dm && id_[e] < im);
      if (better) { dm = d[e]; im = id_[e]; slot = e; }
    }
    idx_out[(size_t)row * 10 + t] = (ushort)im;
#pragma unroll
    for (int e = 0; e < S * 10; ++e)
      if (e == slot) d[e] = FBIG;
  }
}

// ---------- u = x*W_bot ; v = x*(W_top - W_bot) + b  (W staged in LDS) ----------
__global__ __launch_bounds__(256) void uv_kernel(const float* __restrict__ Xf, int CIN,
                                                 const float* __restrict__ W,
                                                 const float* __restrict__ bias,
                                                 float* __restrict__ U, float* __restrict__ V) {
  __shared__ float Ws[8192];  // 2*CIN*64 floats, max 32KB at CIN=64
  int tid = threadIdx.x;
  int c = tid & 63, p = tid >> 6;
  int n = blockIdx.x * 4 + p;
  const int tot = CIN * 128;
  for (int i = tid; i < tot; i += 256) Ws[i] = W[i];
  __syncthreads();
  const float* xr = Xf + (size_t)n * CIN;
  float vt = 0.f, vb = 0.f;
  for (int m = 0; m < CIN; ++m) {
    float xm = xr[m];
    vt = fmaf(xm, Ws[m * 64 + c], vt);
    vb = fmaf(xm, Ws[(CIN + m) * 64 + c], vb);
  }
  U[(size_t)n * 64 + c] = vb;
  V[(size_t)n * 64 + c] = vt - vb + bias[c];
}

// ---------- BN batch stats ----------
__global__ __launch_bounds__(256) void stats_kernel(const float* __restrict__ U,
                                                    const float* __restrict__ V,
                                                    const ushort* __restrict__ idx,
                                                    float* __restrict__ accum) {
  int tid = threadIdx.x;
  int c = tid & 63, p = tid >> 6;
  int base = blockIdx.x * 64;  // 256 blocks x 64 points
  float s = 0.f, s2 = 0.f;
  for (int ch = 0; ch < 16; ++ch) {
    int n = base + ch * 4 + p;
    float vn = V[(size_t)n * 64 + c];
    const ushort* in_ = idx + (size_t)n * 10;
#pragma unroll
    for (int k = 0; k < 10; ++k) {
      float h = vn + U[(size_t)in_[k] * 64 + c];
      s += h;
      s2 = fmaf(h, h, s2);
    }
  }
  __shared__ float red[256], red2[256];
  red[tid] = s; red2[tid] = s2;
  __syncthreads();
  if (tid < 64) {
    float ts = red[tid] + red[64 + tid] + red[128 + tid] + red[192 + tid];
    float t2 = red2[tid] + red2[64 + tid] + red2[128 + tid] + red2[192 + tid];
    atomicAdd(&accum[tid], ts);
    atomicAdd(&accum[64 + tid], t2);
  }
}

__global__ void bnfin_kernel(const float* __restrict__ accum,
                             const float* __restrict__ gamma,
                             const float* __restrict__ beta,
                             float* __restrict__ scale, float* __restrict__ shift) {
  int c = threadIdx.x;  // 64
  float inv = 1.f / (float)(N * KNN);
  float mu = accum[c] * inv;
  float var = accum[64 + c] * inv - mu * mu;
  float sc = gamma[c] * rsqrtf(var + 1e-5f);
  scale[c] = sc;
  shift[c] = fmaf(-mu, sc, beta[c]);
}

// ---------- apply (BN) + ReLU + max over k ----------
__global__ __launch_bounds__(256) void apply_kernel(const float* __restrict__ U,
                                                    const float* __restrict__ V,
                                                    const ushort* __restrict__ idx,
                                                    const float* __restrict__ scale,
                                                    const float* __restrict__ shift,
                                                    int use_bn, float* __restrict__ Fout) {
  int tid = threadIdx.x;
  int c = tid & 63, p = tid >> 6;
  int n = blockIdx.x * 4 + p;
  float sc = use_bn ? scale[c] : 1.f;
  float sh = use_bn ? shift[c] : 0.f;
  float vn = V[(size_t)n * 64 + c];
  const ushort* in_ = idx + (size_t)n * 10;
  float m = 0.f;
#pragma unroll
  for (int k = 0; k < 10; ++k) {
    float h = vn + U[(size_t)in_[k] * 64 + c];
    m = fmaxf(m, fmaf(h, sc, sh));
  }
  Fout[(size_t)n * 64 + c] = m;
}

// ---------- segment max pooling, stage 1 (stage 2 fused into head) ----------
__global__ __launch_bounds__(256) void pool1_kernel(const float* __restrict__ f1,
                                                    const float* __restrict__ f2,
                                                    const float* __restrict__ f3,
                                                    const float* __restrict__ f4,
                                                    const int* __restrict__ n_pts,
                                                    float* __restrict__ Pp) {
  int b = blockIdx.x >> 2;
  int q = blockIdx.x & 3;
  int c = threadIdx.x;
  int off = 0;
  for (int i = 0; i < b; ++i) off += n_pts[i];
  int cnt_ = n_pts[b];
  int s0 = off + (cnt_ * q) / 4;
  int s1 = off + (cnt_ * (q + 1)) / 4;
  const float* f = (c < 64) ? f1 : (c < 128) ? f2 : (c < 192) ? f3 : f4;
  int ch = c & 63;
  float m = -3.4e38f;
  for (int t = s0; t < s1; ++t) m = fmaxf(m, f[(size_t)t * 64 + ch]);
  Pp[((size_t)q * 64 + b) * 256 + c] = m;
}

// ---------- head: 4-way pool max + tanh(P@Wp + bp) + L2 normalize ----------
__global__ __launch_bounds__(128) void head_kernel(const float* __restrict__ Pp,
                                                   const float* __restrict__ Wp,
                                                   const float* __restrict__ bp,
                                                   float* __restrict__ out) {
  int b = blockIdx.x;
  int c = threadIdx.x;
  __shared__ float ps[256];
#pragma unroll
  for (int j = 0; j < 2; ++j) {
    int cc = c + j * 128;
    float m = Pp[(size_t)b * 256 + cc];
#pragma unroll
    for (int q = 1; q < 4; ++q) m = fmaxf(m, Pp[((size_t)q * 64 + b) * 256 + cc]);
    ps[cc] = m;
  }
  __syncthreads();
  float acc = bp[c];
  for (int m = 0; m < 256; ++m) acc = fmaf(ps[m], Wp[m * 128 + c], acc);
  float t = tanhf(acc);
  __shared__ float red[128];
  red[c] = t * t;
  __syncthreads();
  for (int s = 64; s > 0; s >>= 1) {
    if (c < s) red[c] += red[c + s];
    __syncthreads();
  }
  float nrm = sqrtf(red[0]);
  out[b * 128 + c] = t / (nrm + 1e-9f);
}

extern "C" void kernel_launch(void* const* d_in, const int* in_sizes, int n_in,
                              void* d_out, int out_size, void* d_ws, size_t ws_size,
                              hipStream_t stream) {
  const float* x = (const float*)d_in[0];
  const int* n_pts = (const int*)d_in[1];
  const float* W1 = (const float*)d_in[2];
  const float* b1 = (const float*)d_in[3];
  const float* g1 = (const float*)d_in[4];
  const float* be1 = (const float*)d_in[5];
  const float* W2 = (const float*)d_in[6];
  const float* b2 = (const float*)d_in[7];
  const float* W3 = (const float*)d_in[8];
  const float* b3 = (const float*)d_in[9];
  const float* g3 = (const float*)d_in[10];
  const float* be3 = (const float*)d_in[11];
  const float* W4 = (const float*)d_in[12];
  const float* b4 = (const float*)d_in[13];
  const float* Wp = (const float*)d_in[14];
  const float* bp = (const float*)d_in[15];
  float* out = (float*)d_out;

  char* w = (char*)d_ws;
  auto alloc = [&](size_t bytes) {
    char* p = w;
    w += (bytes + 255) & ~(size_t)255;
    return p;
  };
  const size_t FS = (size_t)N * 64 * 4;
  float* f1 = (float*)alloc(FS);
  float* f2 = (float*)alloc(FS);
  float* f3 = (float*)alloc(FS);
  float* f4 = (float*)alloc(FS);
  float* Ub = (float*)alloc(FS);                              // overlaid: Xp128
  float* dpartf = (float*)alloc((size_t)NS64 * N * 10 * 4);   // 7.86 MB
  ushort* iparti = (ushort*)alloc((size_t)NS64 * N * 10 * 2); // 3.93 MB
  float4* xp = (float4*)alloc((size_t)N * 16);
  float* sqb = (float*)alloc((size_t)N * 4);
  int* gtauI = (int*)alloc((size_t)N * 4);
  ushort* idxb = (ushort*)alloc((size_t)N * 10 * 2);
  float* accum = (float*)alloc(512);
  float* scaleb = (float*)alloc(256);
  float* shiftb = (float*)alloc(256);
  float* Ppart = (float*)alloc((size_t)4 * 64 * 256 * 4);
  ushort* Xp128 = (ushort*)Ub;
  // V overlays dpart's first 4 MB: dpart consumed by merge BEFORE uv writes V;
  // V consumed by stats/apply BEFORE the next layer's knn writes dpart.
  float* Vb = dpartf;
  (void)ws_size; (void)n_in; (void)in_sizes; (void)out_size;

  auto run_layer = [&](const float* fin, int cin, const float* W, const float* b,
                       const float* g, const float* be, int use_bn, float* fout) {
    if (cin == 3) {
      pack3_kernel<<<N / 256, 256, 0, stream>>>(fin, xp, gtauI, accum);
      knn3g_kernel<<<64 * NS3, 256, 0, stream>>>(xp, gtauI, dpartf, iparti);
      merge_kernel<NS3><<<N / 256, 256, 0, stream>>>(dpartf, iparti, idxb);
    } else {
      prep128s_kernel<<<N * 64 / 4 / 256, 256, 0, stream>>>(fin, Xp128, sqb, gtauI, accum);
      knn64w_kernel<<<64 * NS64, 256, 0, stream>>>(Xp128, sqb, gtauI, dpartf, iparti);
      merge_kernel<NS64><<<N / 256, 256, 0, stream>>>(dpartf, iparti, idxb);
    }
    uv_kernel<<<N / 4, 256, 0, stream>>>(fin, cin, W, b, Ub, Vb);
    if (use_bn) {
      stats_kernel<<<256, 256, 0, stream>>>(Ub, Vb, idxb, accum);
      bnfin_kernel<<<1, 64, 0, stream>>>(accum, g, be, scaleb, shiftb);
    }
    apply_kernel<<<N / 4, 256, 0, stream>>>(Ub, Vb, idxb, scaleb, shiftb, use_bn, fout);
  };

  run_layer(x, 3, W1, b1, g1, be1, 1, f1);
  run_layer(f1, 64, W2, b2, nullptr, nullptr, 0, f2);
  run_layer(f2, 64, W3, b3, g3, be3, 1, f3);
  run_layer(f3, 64, W4, b4, nullptr, nullptr, 0, f4);
  pool1_kernel<<<256, 256, 0, stream>>>(f1, f2, f3, f4, n_pts, Ppart);
  head_kernel<<<64, 128, 0, stream>>>(Ppart, Wp, bp, out);
}